// Round 4
// baseline (406.937 us; speedup 1.0000x reference)
//
#include <hip/hip_runtime.h>
#include <hip/hip_bf16.h>
#include <math.h>

#define DD 128
#define QW 896       // 256(Q)+256(K)+256(V)+128(skip)
#define CAP 128

typedef _Float16 f16x8 __attribute__((ext_vector_type(8)));
typedef _Float16 f16x4 __attribute__((ext_vector_type(4)));
typedef _Float16 f16x2 __attribute__((ext_vector_type(2)));
typedef float f32x4 __attribute__((ext_vector_type(4)));

__device__ __forceinline__ float fdot2f(f16x2 a, f16x2 b, float c) {
#if __has_builtin(__builtin_amdgcn_fdot2)
  return __builtin_amdgcn_fdot2(a, b, c, false);
#else
  return fmaf((float)a[0], (float)b[0], fmaf((float)a[1], (float)b[1], c));
#endif
}

// ---------------- CSR build ----------------
__global__ __launch_bounds__(256) void count_kernel(const int* __restrict__ edst,
                                                    int* __restrict__ counts, int E) {
  int e = blockIdx.x * 256 + threadIdx.x;
  if (e < E) atomicAdd(&counts[edst[e]], 1);
}

__global__ __launch_bounds__(1024) void scan_kernel(const int* __restrict__ counts,
                                                    int* __restrict__ offs,
                                                    int* __restrict__ cursor, int Nn) {
  __shared__ int part[1024];
  int tid = threadIdx.x;
  int chunk = (Nn + 1023) >> 10;
  int b = tid * chunk, e = min(b + chunk, Nn);
  int s = 0;
  for (int j = b; j < e; ++j) s += counts[j];
  part[tid] = s;
  __syncthreads();
  for (int d = 1; d < 1024; d <<= 1) {
    int v = (tid >= d) ? part[tid - d] : 0;
    __syncthreads();
    part[tid] += v;
    __syncthreads();
  }
  int excl = tid ? part[tid - 1] : 0;
  for (int j = b; j < e; ++j) { offs[j] = excl; cursor[j] = excl; excl += counts[j]; }
  if (tid == 1023) offs[Nn] = part[1023];
}

__global__ __launch_bounds__(256) void scatter_kernel(const int* __restrict__ edst,
                                                      const int* __restrict__ esrc,
                                                      const int* __restrict__ etyp,
                                                      int* __restrict__ cursor,
                                                      unsigned* __restrict__ epk, int E) {
  int e = blockIdx.x * 256 + threadIdx.x;
  if (e < E) {
    int pos = atomicAdd(&cursor[edst[e]], 1);
    epk[pos] = (unsigned)esrc[e] | ((unsigned)etyp[e] << 18);
  }
}

// ---------------- pp_cast: all parallel precompute ----------------
__global__ __launch_bounds__(256) void pp_cast(
    const float* __restrict__ Wq, const float* __restrict__ Wk,
    const float* __restrict__ Wv, const float* __restrict__ Wsk,
    const float* __restrict__ bq, const float* __restrict__ bk,
    const float* __restrict__ bv, const float* __restrict__ bsk,
    const float* __restrict__ hemb, const float* __restrict__ We,
    const float* __restrict__ x,
    const float* __restrict__ fw1, const float* __restrict__ fb1,
    const float* __restrict__ fw2, const float* __restrict__ fb2,
    _Float16* __restrict__ WcatT, float* __restrict__ Wcat, float* __restrict__ bcat,
    _Float16* __restrict__ epth, _Float16* __restrict__ xh,
    _Float16* __restrict__ fw1h, _Float16* __restrict__ fw2Th,
    float* __restrict__ bfv, float* __restrict__ bzero, int Nn) {
  int t = blockIdx.x * 256 + threadIdx.x;
  if (t < 256) {  // bfv[l][j]: 512-dot, 4 accumulators
    int l = t >> 7, j = t & 127;
    const float* b1 = fb1 + l * 512;
    const float* w2 = fw2 + (size_t)l * 65536 + j;
    float s0 = fb2[l * 128 + j], s1 = 0.f, s2 = 0.f, s3 = 0.f;
    for (int k = 0; k < 512; k += 4) {
      s0 = fmaf(b1[k], w2[(size_t)k * 128], s0);
      s1 = fmaf(b1[k + 1], w2[(size_t)(k + 1) * 128], s1);
      s2 = fmaf(b1[k + 2], w2[(size_t)(k + 2) * 128], s2);
      s3 = fmaf(b1[k + 3], w2[(size_t)(k + 3) * 128], s3);
    }
    bfv[t] = ((s0 + s1) + (s2 + s3));
    return;
  }
  t -= 256;
  if (t < 2560) {  // eproj
    int ty = t >> 8, col = t & 255;
    float s0 = 0.f, s1 = 0.f, s2 = 0.f, s3 = 0.f;
    const float* hr = hemb + ty * 128;
    for (int c = 0; c < 128; c += 4) {
      s0 = fmaf(hr[c], We[c * 256 + col], s0);
      s1 = fmaf(hr[c + 1], We[(c + 1) * 256 + col], s1);
      s2 = fmaf(hr[c + 2], We[(c + 2) * 256 + col], s2);
      s3 = fmaf(hr[c + 3], We[(c + 3) * 256 + col], s3);
    }
    epth[t] = (_Float16)((s0 + s1) + (s2 + s3));
    return;
  }
  t -= 2560;
  if (t < 114688) {  // WcatT f16 [896][128] + Wcat f32 [128][896]
    int n = t >> 7, k = t & 127;
    float v;
    if (n < 256) v = Wq[k * 256 + n];
    else if (n < 512) v = Wk[k * 256 + (n - 256)];
    else if (n < 768) v = Wv[k * 256 + (n - 512)];
    else v = Wsk[k * 128 + (n - 768)];
    WcatT[t] = (_Float16)v;
    Wcat[k * 896 + n] = v;
    return;
  }
  t -= 114688;
  if (t < 896) {
    float v;
    if (t < 256) v = bq[t];
    else if (t < 512) v = bk[t - 256];
    else if (t < 768) v = bv[t - 512];
    else v = bsk[t - 768];
    bcat[t] = v;
    return;
  }
  t -= 896;
  if (t < 1024) { bzero[t] = 0.f; return; }
  t -= 1024;
  if (t < 16384) {  // fw1 cast, 8/thread
    float4 v0 = *reinterpret_cast<const float4*>(fw1 + (size_t)t * 8);
    float4 v1 = *reinterpret_cast<const float4*>(fw1 + (size_t)t * 8 + 4);
    f16x8 o;
    o[0] = (_Float16)v0.x; o[1] = (_Float16)v0.y; o[2] = (_Float16)v0.z; o[3] = (_Float16)v0.w;
    o[4] = (_Float16)v1.x; o[5] = (_Float16)v1.y; o[6] = (_Float16)v1.z; o[7] = (_Float16)v1.w;
    *reinterpret_cast<f16x8*>(fw1h + (size_t)t * 8) = o;
    return;
  }
  t -= 16384;
  if (t < 131072) {  // fw2 transpose+cast: fw2Th[l][j][k] = fw2[l][k][j]
    int l = t >> 16, rem = t & 65535;
    int j = rem >> 9, k = rem & 511;
    fw2Th[t] = (_Float16)fw2[(size_t)l * 65536 + (size_t)k * 128 + j];
    return;
  }
  t -= 131072;
  if (t < Nn * 16) {  // cast x -> f16, 8/thread
    float4 v0 = *reinterpret_cast<const float4*>(x + (size_t)t * 8);
    float4 v1 = *reinterpret_cast<const float4*>(x + (size_t)t * 8 + 4);
    f16x8 o;
    o[0] = (_Float16)v0.x; o[1] = (_Float16)v0.y; o[2] = (_Float16)v0.z; o[3] = (_Float16)v0.w;
    o[4] = (_Float16)v1.x; o[5] = (_Float16)v1.y; o[6] = (_Float16)v1.z; o[7] = (_Float16)v1.w;
    *reinterpret_cast<f16x8*>(xh + (size_t)t * 8) = o;
  }
}

// ---------------- pp_bmid: bmid = [bfv0 | bfv0@Wcat + bcat] ----------------
__global__ __launch_bounds__(256) void pp_bmid(const float* __restrict__ bfv,
                                               const float* __restrict__ Wcat,
                                               const float* __restrict__ bcat,
                                               float* __restrict__ bmid) {
  int t = blockIdx.x * 256 + threadIdx.x;
  if (t >= 1024) return;
  if (t < 128) { bmid[t] = bfv[t]; return; }
  int n = t - 128;
  float s0 = bcat[n], s1 = 0.f, s2 = 0.f, s3 = 0.f;
  for (int c = 0; c < 128; c += 4) {
    s0 = fmaf(bfv[c], Wcat[c * 896 + n], s0);
    s1 = fmaf(bfv[c + 1], Wcat[(c + 1) * 896 + n], s1);
    s2 = fmaf(bfv[c + 2], Wcat[(c + 2) * 896 + n], s2);
    s3 = fmaf(bfv[c + 3], Wcat[(c + 3) * 896 + n], s3);
  }
  bmid[t] = ((s0 + s1) + (s2 + s3));
}

// ---------------- MFMA f16 GEMM: C = A[M,K] @ Bt[N,K]^T + bias ----------------
// Outputs: Cf (f32, cols<NF), Ch (f16, cols>=choff, stride ldh), ChT (f16 transposed, ChT[col*ldt+row])
__global__ __launch_bounds__(256) void gemm_tn_f16(const _Float16* __restrict__ A,
                                                   const _Float16* __restrict__ Bt,
                                                   const float* __restrict__ bias,
                                                   float* __restrict__ Cf, int NF,
                                                   _Float16* __restrict__ Ch, int choff, int ldh,
                                                   _Float16* __restrict__ ChT, int ldt,
                                                   int M, int N, int K) {
  const int tid = threadIdx.x;
  const int wid = tid >> 6, lane = tid & 63;
  const int wr = wid >> 1, wc = wid & 1;
  const int il = lane & 15, g = lane >> 4;
  const int row0 = blockIdx.x * 128 + wr * 64;
  const int col0 = blockIdx.y * 128 + wc * 64;
  const bool arow_ok = (row0 + il + 48) < M || true;
  (void)arow_ok;
  const _Float16* Ap = A + (size_t)(row0 + il) * K + 8 * g;
  const _Float16* Bp = Bt + (size_t)(col0 + il) * K + 8 * g;
  f32x4 acc[4][4];
#pragma unroll
  for (int a = 0; a < 4; ++a)
#pragma unroll
    for (int b = 0; b < 4; ++b) acc[a][b] = (f32x4){0.f, 0.f, 0.f, 0.f};
  for (int k0 = 0; k0 < K; k0 += 32) {
    f16x8 af[4], bf[4];
#pragma unroll
    for (int f = 0; f < 4; ++f) {
      af[f] = (row0 + f * 16 + il) < M ? *reinterpret_cast<const f16x8*>(Ap + (size_t)(f * 16) * K + k0)
                                       : (f16x8){0, 0, 0, 0, 0, 0, 0, 0};
      bf[f] = *reinterpret_cast<const f16x8*>(Bp + (size_t)(f * 16) * K + k0);
    }
#pragma unroll
    for (int fi = 0; fi < 4; ++fi)
#pragma unroll
      for (int fj = 0; fj < 4; ++fj)
        acc[fi][fj] = __builtin_amdgcn_mfma_f32_16x16x32_f16(af[fi], bf[fj], acc[fi][fj], 0, 0, 0);
  }
#pragma unroll
  for (int fj = 0; fj < 4; ++fj) {
    const int col = col0 + fj * 16 + il;
    const float b = bias[col];
#pragma unroll
    for (int fi = 0; fi < 4; ++fi) {
#pragma unroll
      for (int i = 0; i < 4; ++i) {
        const int row = row0 + fi * 16 + g * 4 + i;
        if (row >= M) continue;
        const float v = acc[fi][fj][i] + b;
        if (Cf && col < NF) Cf[(size_t)row * NF + col] = v;
        if (Ch && col >= choff) Ch[(size_t)row * ldh + (col - choff)] = (_Float16)v;
        if (ChT) ChT[(size_t)col * ldt + row] = (_Float16)v;
      }
    }
  }
}

// ---------------- fused per-node attention + head-mean + skip + residual + LN -------
// One wave per node. QK phase: 4 lanes/edge, 16 edges in flight, fdot2.
// V phase: 32 lanes/edge (8 ch), 2 edge slots, ept folded via per-type alpha-sums.
__global__ __launch_bounds__(256) void node_attn_ln_kernel(
    const _Float16* __restrict__ QKVSh, const _Float16* __restrict__ epth,
    const float* __restrict__ hpre,
    const int* __restrict__ offs, const unsigned* __restrict__ epk,
    const float* __restrict__ gamma, const float* __restrict__ beta,
    _Float16* __restrict__ hlnh, int Nn) {
  __shared__ float slA[4][CAP], slB[4][CAP];
  __shared__ unsigned spk[4][CAP];
  __shared__ float stA[4][10], stB[4][10];
  __shared__ __align__(16) _Float16 elds[2560];
  const int tid = threadIdx.x;
  for (int t = tid; t < 1280; t += 256)
    reinterpret_cast<unsigned*>(elds)[t] = reinterpret_cast<const unsigned*>(epth)[t];
  __syncthreads();
  const int w = tid >> 6, lane = tid & 63;
  const int i = blockIdx.x * 4 + w;
  // QK layout
  const int et = lane >> 2, cl = lane & 3, cbase = cl << 6;
  // V layout
  const int sub = lane >> 5, r = lane & 31, half = r >> 4, co = r << 3;
  const float scale = 0.08838834764831845f;  // 1/sqrt(128)
  f16x8 q8[8];
  {
    const _Float16* qp = QKVSh + (size_t)i * QW + cbase;
#pragma unroll
    for (int c = 0; c < 8; ++c) q8[c] = *reinterpret_cast<const f16x8*>(qp + c * 8);
  }
  float m0 = -1e30f, m1 = -1e30f, s0 = 0.f, s1 = 0.f;
  float acc[8] = {0.f};
  const int ebeg = offs[i], eend = offs[i + 1];
  for (int cs = ebeg; cs < eend; cs += CAP) {
    const int cnt = min(CAP, eend - cs);
    for (int j = lane; j < cnt; j += 64) spk[w][j] = epk[cs + j];
    if (lane < 10) { stA[w][lane] = 0.f; stB[w][lane] = 0.f; }
    __threadfence_block();
    // ---- QK phase: tiles of 16 edges ----
    float tmax = -1e30f;
    for (int j0 = 0; j0 < cnt; j0 += 16) {
      const int j = j0 + et;
      const bool valid = j < cnt;
      const unsigned pk = spk[w][valid ? j : cnt - 1];
      const _Float16* kp = QKVSh + (size_t)(pk & 0x3FFFF) * QW + 256 + cbase;
      const _Float16* ep = elds + ((pk >> 18) << 8) + cbase;
      f16x8 kv[8];
#pragma unroll
      for (int c = 0; c < 8; ++c) kv[c] = *reinterpret_cast<const f16x8*>(kp + c * 8);
      float d = 0.f;
#pragma unroll
      for (int c = 0; c < 8; ++c) {
        f16x8 sum = kv[c] + *reinterpret_cast<const f16x8*>(ep + c * 8);
        const f16x2* sp = reinterpret_cast<const f16x2*>(&sum);
        const f16x2* qp2 = reinterpret_cast<const f16x2*>(&q8[c]);
#pragma unroll
        for (int p2 = 0; p2 < 4; ++p2) d = fdot2f(qp2[p2], sp[p2], d);
      }
      d += __shfl_xor(d, 1);  // pair-sum -> full per-head dot (cl0,1 = head0; cl2,3 = head1)
      d *= scale;
      if (valid) {
        if (cl == 0) slA[w][j] = d;
        else if (cl == 2) slB[w][j] = d;
        tmax = fmaxf(tmax, d);
      }
    }
#pragma unroll
    for (int o = 4; o <= 32; o <<= 1) tmax = fmaxf(tmax, __shfl_xor(tmax, o));
    const float tOther = __shfl_xor(tmax, 2);
    const float cm0 = (lane & 2) ? tOther : tmax;
    const float cm1 = (lane & 2) ? tmax : tOther;
    const float nm0 = fmaxf(m0, cm0), nm1 = fmaxf(m1, cm1);
    const float r0 = __expf(m0 - nm0), r1 = __expf(m1 - nm1);
    const float rme = half ? r1 : r0;
    s0 *= r0; s1 *= r1;
#pragma unroll
    for (int t = 0; t < 8; ++t) acc[t] *= rme;
    m0 = nm0; m1 = nm1;
    __threadfence_block();
    // ---- exp pass + per-type alpha sums ----
    float ls0 = 0.f, ls1 = 0.f;
    for (int j = lane; j < cnt; j += 64) {
      float e0 = __expf(slA[w][j] - m0);
      float e1 = __expf(slB[w][j] - m1);
      slA[w][j] = e0; slB[w][j] = e1;
      ls0 += e0; ls1 += e1;
      int ty = spk[w][j] >> 18;
      atomicAdd(&stA[w][ty], e0);
      atomicAdd(&stB[w][ty], e1);
    }
#pragma unroll
    for (int o = 32; o; o >>= 1) { ls0 += __shfl_xor(ls0, o); ls1 += __shfl_xor(ls1, o); }
    s0 += ls0; s1 += ls1;
    __threadfence_block();
    // ---- V phase: 2 edge slots, prefetch depth 2, pure v*alpha ----
    {
      f16x8 v0 = *reinterpret_cast<const f16x8*>(
          QKVSh + (size_t)(spk[w][min(sub, cnt - 1)] & 0x3FFFF) * QW + 512 + co);
      f16x8 v1 = *reinterpret_cast<const f16x8*>(
          QKVSh + (size_t)(spk[w][min(2 + sub, cnt - 1)] & 0x3FFFF) * QW + 512 + co);
      for (int j = 0; j < cnt; j += 2) {
        f16x8 cur = v0; v0 = v1;
        v1 = *reinterpret_cast<const f16x8*>(
            QKVSh + (size_t)(spk[w][min(j + 4 + sub, cnt - 1)] & 0x3FFFF) * QW + 512 + co);
        const int jj = j + sub;
        const float wj = (jj < cnt) ? (half ? slB[w][jj] : slA[w][jj]) : 0.f;
#pragma unroll
        for (int t = 0; t < 8; ++t) acc[t] = fmaf((float)cur[t], wj, acc[t]);
      }
    }
    // ---- per-type ept epilogue ----
#pragma unroll
    for (int ty = 0; ty < 10; ++ty) {
      const float a = half ? stB[w][ty] : stA[w][ty];
      f16x8 ev = *reinterpret_cast<const f16x8*>(elds + (ty << 8) + co);
#pragma unroll
      for (int t = 0; t < 8; ++t) acc[t] = fmaf((float)ev[t], a, acc[t]);
    }
  }
  // combine slots, normalize, head-mean
  const float inv0 = 1.f / (s0 + 1e-16f), inv1 = 1.f / (s1 + 1e-16f);
  const float invme = half ? inv1 : inv0;
  float g[8];
#pragma unroll
  for (int t = 0; t < 8; ++t) {
    float a = acc[t] + __shfl_xor(acc[t], 32);
    a *= invme;
    g[t] = 0.5f * (a + __shfl_xor(a, 16));
  }
  const int cm = (r & 15) << 3;
  f16x8 sk = *reinterpret_cast<const f16x8*>(QKVSh + (size_t)i * QW + 768 + cm);
  float4 p0 = *reinterpret_cast<const float4*>(hpre + (size_t)i * DD + cm);
  float4 p1 = *reinterpret_cast<const float4*>(hpre + (size_t)i * DD + cm + 4);
  float xv[8];
  xv[0] = g[0] + (float)sk[0] + p0.x; xv[1] = g[1] + (float)sk[1] + p0.y;
  xv[2] = g[2] + (float)sk[2] + p0.z; xv[3] = g[3] + (float)sk[3] + p0.w;
  xv[4] = g[4] + (float)sk[4] + p1.x; xv[5] = g[5] + (float)sk[5] + p1.y;
  xv[6] = g[6] + (float)sk[6] + p1.z; xv[7] = g[7] + (float)sk[7] + p1.w;
  float sm = 0.f;
#pragma unroll
  for (int t = 0; t < 8; ++t) sm += xv[t];
  sm += __shfl_xor(sm, 1); sm += __shfl_xor(sm, 2);
  sm += __shfl_xor(sm, 4); sm += __shfl_xor(sm, 8);
  const float mu = sm * (1.f / 128.f);
  float dx[8], vvs = 0.f;
#pragma unroll
  for (int t = 0; t < 8; ++t) { dx[t] = xv[t] - mu; vvs += dx[t] * dx[t]; }
  vvs += __shfl_xor(vvs, 1); vvs += __shfl_xor(vvs, 2);
  vvs += __shfl_xor(vvs, 4); vvs += __shfl_xor(vvs, 8);
  const float rstd = rsqrtf(vvs * (1.f / 128.f) + 1e-6f);
  if (lane < 16) {
    float4 gm0 = *reinterpret_cast<const float4*>(gamma + cm);
    float4 gm1 = *reinterpret_cast<const float4*>(gamma + cm + 4);
    float4 bt0 = *reinterpret_cast<const float4*>(beta + cm);
    float4 bt1 = *reinterpret_cast<const float4*>(beta + cm + 4);
    f16x8 o;
    o[0] = (_Float16)(dx[0] * rstd * gm0.x + bt0.x);
    o[1] = (_Float16)(dx[1] * rstd * gm0.y + bt0.y);
    o[2] = (_Float16)(dx[2] * rstd * gm0.z + bt0.z);
    o[3] = (_Float16)(dx[3] * rstd * gm0.w + bt0.w);
    o[4] = (_Float16)(dx[4] * rstd * gm1.x + bt1.x);
    o[5] = (_Float16)(dx[5] * rstd * gm1.y + bt1.y);
    o[6] = (_Float16)(dx[6] * rstd * gm1.z + bt1.z);
    o[7] = (_Float16)(dx[7] * rstd * gm1.w + bt1.w);
    *reinterpret_cast<f16x8*>(hlnh + (size_t)i * DD + cm) = o;
  }
}

// ---------------- final: gather mask rows of hln1, apply layer-1 fused FFN ----------------
__global__ __launch_bounds__(128) void final_kernel(const _Float16* __restrict__ hlnh1,
                                                    const float* __restrict__ Wf,
                                                    const float* __restrict__ bfv,
                                                    const int* __restrict__ midx,
                                                    float* __restrict__ out) {
  __shared__ float rowv[128];
  const int b = blockIdx.x, j = threadIdx.x;
  const int row = midx[b];
  rowv[j] = (float)hlnh1[(size_t)row * DD + j];
  __syncthreads();
  const float* w1 = Wf + 16384 + j;  // Wf1[c][j]
  float s = bfv[128 + j];
#pragma unroll 4
  for (int c = 0; c < 128; ++c) s = fmaf(rowv[c], w1[c * 128], s);
  out[b * DD + j] = s;
}

extern "C" void kernel_launch(void* const* d_in, const int* in_sizes, int n_in,
                              void* d_out, int out_size, void* d_ws, size_t ws_size,
                              hipStream_t stream) {
  const float* x    = (const float*)d_in[0];
  const float* hemb = (const float*)d_in[1];
  const float* Wq   = (const float*)d_in[2];
  const float* bq   = (const float*)d_in[3];
  const float* Wk   = (const float*)d_in[4];
  const float* bk   = (const float*)d_in[5];
  const float* Wv   = (const float*)d_in[6];
  const float* bv   = (const float*)d_in[7];
  const float* We   = (const float*)d_in[8];
  const float* Wsk  = (const float*)d_in[9];
  const float* bsk  = (const float*)d_in[10];
  const float* lng  = (const float*)d_in[11];
  const float* lnb  = (const float*)d_in[12];
  const float* fw1  = (const float*)d_in[13];
  const float* fb1  = (const float*)d_in[14];
  const float* fw2  = (const float*)d_in[15];
  const float* fb2  = (const float*)d_in[16];
  const int* eidx   = (const int*)d_in[17];
  const int* etyp   = (const int*)d_in[18];
  const int* midx   = (const int*)d_in[19];

  const int Nn = in_sizes[0] / DD;     // 16000
  const int E = in_sizes[18];          // 256000

  const int* esrc = eidx;
  const int* edst = eidx + E;

  char* p = (char*)d_ws;
  auto alloc = [&](size_t bytes) -> void* {
    void* r = (void*)p;
    p += (bytes + 255) & ~(size_t)255;
    return r;
  };
  _Float16* QKVSh = (_Float16*)alloc((size_t)Nn * QW * 2);
  _Float16* xh    = (_Float16*)alloc((size_t)Nn * DD * 2);
  _Float16* hln0  = (_Float16*)alloc((size_t)Nn * DD * 2);
  _Float16* hln1  = (_Float16*)alloc((size_t)Nn * DD * 2);
  float*    h1    = (float*)alloc((size_t)Nn * DD * 4);
  _Float16* WcatT = (_Float16*)alloc((size_t)QW * DD * 2);
  float*    Wcat  = (float*)alloc((size_t)DD * QW * 4);
  float*    bcat  = (float*)alloc(QW * 4);
  _Float16* epth  = (_Float16*)alloc(2560 * 2);
  _Float16* fw1h  = (_Float16*)alloc((size_t)2 * DD * 512 * 2);
  _Float16* fw2Th = (_Float16*)alloc((size_t)2 * DD * 512 * 2);
  float*    Wf    = (float*)alloc(2 * 128 * 128 * 4);
  _Float16* Wfh   = (_Float16*)alloc(128 * 128 * 2);
  float*    bfv   = (float*)alloc(256 * 4);
  float*    bzero = (float*)alloc(1024 * 4);
  _Float16* BtMid = (_Float16*)alloc((size_t)1024 * 128 * 2);
  float*    bmid  = (float*)alloc(1024 * 4);
  int* counts = (int*)alloc((size_t)Nn * 4);
  int* offs   = (int*)alloc((size_t)(Nn + 1) * 4);
  int* cursor = (int*)alloc((size_t)Nn * 4);
  unsigned* epk = (unsigned*)alloc((size_t)E * 4);

  // CSR
  hipMemsetAsync(counts, 0, (size_t)Nn * sizeof(int), stream);
  count_kernel<<<(E + 255) / 256, 256, 0, stream>>>(edst, counts, E);
  scan_kernel<<<1, 1024, 0, stream>>>(counts, offs, cursor, Nn);
  scatter_kernel<<<(E + 255) / 256, 256, 0, stream>>>(edst, esrc, etyp, cursor, epk, E);

  // Precompute
  const int pc_threads = 256 + 2560 + 114688 + 896 + 1024 + 16384 + 131072 + Nn * 16;
  pp_cast<<<(pc_threads + 255) / 256, 256, 0, stream>>>(
      Wq, Wk, Wv, Wsk, bq, bk, bv, bsk, hemb, We, x, fw1, fb1, fw2, fb2,
      WcatT, Wcat, bcat, epth, xh, fw1h, fw2Th, bfv, bzero, Nn);
  pp_bmid<<<4, 256, 0, stream>>>(bfv, Wcat, bcat, bmid);
  // Wf[l] = fw1[l] @ fw2[l] (MFMA); l=0 also emits Wfh + BtMid[0:128] (transposed)
  gemm_tn_f16<<<dim3(1, 1), 256, 0, stream>>>(fw1h, fw2Th, bzero,
                                              Wf, 128, Wfh, 0, 128, BtMid, 128,
                                              128, 128, 512);
  gemm_tn_f16<<<dim3(1, 1), 256, 0, stream>>>(fw1h + 65536, fw2Th + 65536, bzero,
                                              Wf + 16384, 128, nullptr, 0, 0, nullptr, 0,
                                              128, 128, 512);
  // BtMid[128:1024] = (Wf0 @ Wcat)^T
  gemm_tn_f16<<<dim3(1, 7), 256, 0, stream>>>(Wfh, WcatT, bzero,
                                              nullptr, 0, nullptr, 0, 0, BtMid + 16384, 128,
                                              128, 896, 128);

  // Layer 0
  dim3 g1((Nn + 127) / 128, QW / 128);
  gemm_tn_f16<<<g1, 256, 0, stream>>>(xh, WcatT, bcat, nullptr, 0, QKVSh, 0, QW,
                                      nullptr, 0, Nn, QW, DD);
  node_attn_ln_kernel<<<Nn / 4, 256, 0, stream>>>(QKVSh, epth, x, offs, epk,
                                                  lng, lnb, hln0, Nn);
  // Fused: [h1 (f32) | QKVS1 (f16)] = hln0 @ [Wf0 | Wf0@Wcat] + bmid
  dim3 g2((Nn + 127) / 128, 1024 / 128);
  gemm_tn_f16<<<g2, 256, 0, stream>>>(hln0, BtMid, bmid, h1, 128, QKVSh, 128, QW,
                                      nullptr, 0, Nn, 1024, DD);
  node_attn_ln_kernel<<<Nn / 4, 256, 0, stream>>>(QKVSh, epth, h1, offs, epk,
                                                  lng + DD, lnb + DD, hln1, Nn);
  final_kernel<<<64, 128, 0, stream>>>(hln1, Wf, bfv, midx, (float*)d_out);
}

// Round 5
// 313.226 us; speedup vs baseline: 1.2992x; 1.2992x over previous
//
#include <hip/hip_runtime.h>
#include <hip/hip_bf16.h>
#include <math.h>

#define DD 128
#define QW 896       // 256(Q)+256(K)+256(V)+128(skip)
#define CAP 96

typedef _Float16 f16x8 __attribute__((ext_vector_type(8)));
typedef _Float16 f16x4 __attribute__((ext_vector_type(4)));
typedef _Float16 f16x2 __attribute__((ext_vector_type(2)));
typedef float f32x4 __attribute__((ext_vector_type(4)));

__device__ __forceinline__ float fdot2f(f16x2 a, f16x2 b, float c) {
#if __has_builtin(__builtin_amdgcn_fdot2)
  return __builtin_amdgcn_fdot2(a, b, c, false);
#else
  return fmaf((float)a[0], (float)b[0], fmaf((float)a[1], (float)b[1], c));
#endif
}

// ---------------- CSR build ----------------
__global__ __launch_bounds__(256) void count_kernel(const int* __restrict__ edst,
                                                    int* __restrict__ counts, int E) {
  int e = blockIdx.x * 256 + threadIdx.x;
  if (e < E) atomicAdd(&counts[edst[e]], 1);
}

__global__ __launch_bounds__(1024) void scan_kernel(const int* __restrict__ counts,
                                                    int* __restrict__ offs,
                                                    int* __restrict__ cursor, int Nn) {
  __shared__ int part[1024];
  int tid = threadIdx.x;
  int chunk = (Nn + 1023) >> 10;
  int b = tid * chunk, e = min(b + chunk, Nn);
  int s = 0;
  for (int j = b; j < e; ++j) s += counts[j];
  part[tid] = s;
  __syncthreads();
  for (int d = 1; d < 1024; d <<= 1) {
    int v = (tid >= d) ? part[tid - d] : 0;
    __syncthreads();
    part[tid] += v;
    __syncthreads();
  }
  int excl = tid ? part[tid - 1] : 0;
  for (int j = b; j < e; ++j) { offs[j] = excl; cursor[j] = excl; excl += counts[j]; }
  if (tid == 1023) offs[Nn] = part[1023];
}

__global__ __launch_bounds__(256) void scatter_kernel(const int* __restrict__ edst,
                                                      const int* __restrict__ esrc,
                                                      const int* __restrict__ etyp,
                                                      int* __restrict__ cursor,
                                                      unsigned* __restrict__ epk, int E) {
  int e = blockIdx.x * 256 + threadIdx.x;
  if (e < E) {
    int pos = atomicAdd(&cursor[edst[e]], 1);
    epk[pos] = (unsigned)esrc[e] | ((unsigned)etyp[e] << 18);
  }
}

// ---------------- pp_cast: all parallel precompute ----------------
__global__ __launch_bounds__(256) void pp_cast(
    const float* __restrict__ Wq, const float* __restrict__ Wk,
    const float* __restrict__ Wv, const float* __restrict__ Wsk,
    const float* __restrict__ bq, const float* __restrict__ bk,
    const float* __restrict__ bv, const float* __restrict__ bsk,
    const float* __restrict__ hemb, const float* __restrict__ We,
    const float* __restrict__ x,
    const float* __restrict__ fw1, const float* __restrict__ fb1,
    const float* __restrict__ fw2, const float* __restrict__ fb2,
    _Float16* __restrict__ WcatT, float* __restrict__ Wcat, float* __restrict__ bcat,
    _Float16* __restrict__ epth, _Float16* __restrict__ xh,
    _Float16* __restrict__ fw1h, _Float16* __restrict__ fw2Th,
    float* __restrict__ bfv, float* __restrict__ bzero, int Nn) {
  int t = blockIdx.x * 256 + threadIdx.x;
  if (t < 256) {  // bfv[l][j]: 512-dot, 4 accumulators
    int l = t >> 7, j = t & 127;
    const float* b1 = fb1 + l * 512;
    const float* w2 = fw2 + (size_t)l * 65536 + j;
    float s0 = fb2[l * 128 + j], s1 = 0.f, s2 = 0.f, s3 = 0.f;
    for (int k = 0; k < 512; k += 4) {
      s0 = fmaf(b1[k], w2[(size_t)k * 128], s0);
      s1 = fmaf(b1[k + 1], w2[(size_t)(k + 1) * 128], s1);
      s2 = fmaf(b1[k + 2], w2[(size_t)(k + 2) * 128], s2);
      s3 = fmaf(b1[k + 3], w2[(size_t)(k + 3) * 128], s3);
    }
    bfv[t] = ((s0 + s1) + (s2 + s3));
    return;
  }
  t -= 256;
  if (t < 2560) {  // eproj
    int ty = t >> 8, col = t & 255;
    float s0 = 0.f, s1 = 0.f, s2 = 0.f, s3 = 0.f;
    const float* hr = hemb + ty * 128;
    for (int c = 0; c < 128; c += 4) {
      s0 = fmaf(hr[c], We[c * 256 + col], s0);
      s1 = fmaf(hr[c + 1], We[(c + 1) * 256 + col], s1);
      s2 = fmaf(hr[c + 2], We[(c + 2) * 256 + col], s2);
      s3 = fmaf(hr[c + 3], We[(c + 3) * 256 + col], s3);
    }
    epth[t] = (_Float16)((s0 + s1) + (s2 + s3));
    return;
  }
  t -= 2560;
  if (t < 114688) {  // WcatT f16 [896][128] + Wcat f32 [128][896]
    int n = t >> 7, k = t & 127;
    float v;
    if (n < 256) v = Wq[k * 256 + n];
    else if (n < 512) v = Wk[k * 256 + (n - 256)];
    else if (n < 768) v = Wv[k * 256 + (n - 512)];
    else v = Wsk[k * 128 + (n - 768)];
    WcatT[t] = (_Float16)v;
    Wcat[k * 896 + n] = v;
    return;
  }
  t -= 114688;
  if (t < 896) {
    float v;
    if (t < 256) v = bq[t];
    else if (t < 512) v = bk[t - 256];
    else if (t < 768) v = bv[t - 512];
    else v = bsk[t - 768];
    bcat[t] = v;
    return;
  }
  t -= 896;
  if (t < 1024) { bzero[t] = 0.f; return; }
  t -= 1024;
  if (t < 16384) {  // fw1 cast, 8/thread
    float4 v0 = *reinterpret_cast<const float4*>(fw1 + (size_t)t * 8);
    float4 v1 = *reinterpret_cast<const float4*>(fw1 + (size_t)t * 8 + 4);
    f16x8 o;
    o[0] = (_Float16)v0.x; o[1] = (_Float16)v0.y; o[2] = (_Float16)v0.z; o[3] = (_Float16)v0.w;
    o[4] = (_Float16)v1.x; o[5] = (_Float16)v1.y; o[6] = (_Float16)v1.z; o[7] = (_Float16)v1.w;
    *reinterpret_cast<f16x8*>(fw1h + (size_t)t * 8) = o;
    return;
  }
  t -= 16384;
  if (t < 131072) {  // fw2 transpose+cast: fw2Th[l][j][k] = fw2[l][k][j]
    int l = t >> 16, rem = t & 65535;
    int j = rem >> 9, k = rem & 511;
    fw2Th[t] = (_Float16)fw2[(size_t)l * 65536 + (size_t)k * 128 + j];
    return;
  }
  t -= 131072;
  if (t < Nn * 16) {  // cast x -> f16, 8/thread
    float4 v0 = *reinterpret_cast<const float4*>(x + (size_t)t * 8);
    float4 v1 = *reinterpret_cast<const float4*>(x + (size_t)t * 8 + 4);
    f16x8 o;
    o[0] = (_Float16)v0.x; o[1] = (_Float16)v0.y; o[2] = (_Float16)v0.z; o[3] = (_Float16)v0.w;
    o[4] = (_Float16)v1.x; o[5] = (_Float16)v1.y; o[6] = (_Float16)v1.z; o[7] = (_Float16)v1.w;
    *reinterpret_cast<f16x8*>(xh + (size_t)t * 8) = o;
  }
}

// ---------------- pp_bmid: bmid = [bfv0 | bfv0@Wcat + bcat] ----------------
__global__ __launch_bounds__(256) void pp_bmid(const float* __restrict__ bfv,
                                               const float* __restrict__ Wcat,
                                               const float* __restrict__ bcat,
                                               float* __restrict__ bmid) {
  int t = blockIdx.x * 256 + threadIdx.x;
  if (t >= 1024) return;
  if (t < 128) { bmid[t] = bfv[t]; return; }
  int n = t - 128;
  float s0 = bcat[n], s1 = 0.f, s2 = 0.f, s3 = 0.f;
  for (int c = 0; c < 128; c += 4) {
    s0 = fmaf(bfv[c], Wcat[c * 896 + n], s0);
    s1 = fmaf(bfv[c + 1], Wcat[(c + 1) * 896 + n], s1);
    s2 = fmaf(bfv[c + 2], Wcat[(c + 2) * 896 + n], s2);
    s3 = fmaf(bfv[c + 3], Wcat[(c + 3) * 896 + n], s3);
  }
  bmid[t] = ((s0 + s1) + (s2 + s3));
}

// ---------------- MFMA f16 GEMM: C = A[M,K] @ Bt[N,K]^T + bias ----------------
// Assumes M%128==0, N%128==0, K%32==0.
// Outputs: Cf (f32, cols<NF), Ch (f16, cols>=choff, stride ldh), ChT (f16, ChT[col*ldt+row])
__global__ __launch_bounds__(256) void gemm_tn_f16(const _Float16* __restrict__ A,
                                                   const _Float16* __restrict__ Bt,
                                                   const float* __restrict__ bias,
                                                   float* __restrict__ Cf, int NF,
                                                   _Float16* __restrict__ Ch, int choff, int ldh,
                                                   _Float16* __restrict__ ChT, int ldt,
                                                   int M, int N, int K) {
  const int tid = threadIdx.x;
  const int wid = tid >> 6, lane = tid & 63;
  const int wr = wid >> 1, wc = wid & 1;
  const int il = lane & 15, g = lane >> 4;
  const int row0 = blockIdx.x * 128 + wr * 64;
  const int col0 = blockIdx.y * 128 + wc * 64;
  const _Float16* Ap = A + (size_t)(row0 + il) * K + 8 * g;
  const _Float16* Bp = Bt + (size_t)(col0 + il) * K + 8 * g;
  f32x4 acc[4][4];
#pragma unroll
  for (int a = 0; a < 4; ++a)
#pragma unroll
    for (int b = 0; b < 4; ++b) acc[a][b] = (f32x4){0.f, 0.f, 0.f, 0.f};
  for (int k0 = 0; k0 < K; k0 += 32) {
    f16x8 af[4], bf[4];
#pragma unroll
    for (int f = 0; f < 4; ++f) {
      af[f] = *reinterpret_cast<const f16x8*>(Ap + (size_t)(f * 16) * K + k0);
      bf[f] = *reinterpret_cast<const f16x8*>(Bp + (size_t)(f * 16) * K + k0);
    }
#pragma unroll
    for (int fi = 0; fi < 4; ++fi)
#pragma unroll
      for (int fj = 0; fj < 4; ++fj)
        acc[fi][fj] = __builtin_amdgcn_mfma_f32_16x16x32_f16(af[fi], bf[fj], acc[fi][fj], 0, 0, 0);
  }
#pragma unroll
  for (int fj = 0; fj < 4; ++fj) {
    const int col = col0 + fj * 16 + il;
    const float b = bias[col];
#pragma unroll
    for (int fi = 0; fi < 4; ++fi) {
#pragma unroll
      for (int i = 0; i < 4; ++i) {
        const int row = row0 + fi * 16 + g * 4 + i;
        const float v = acc[fi][fj][i] + b;
        if (Cf && col < NF) Cf[(size_t)row * NF + col] = v;
        if (Ch && col >= choff) Ch[(size_t)row * ldh + (col - choff)] = (_Float16)v;
        if (ChT) ChT[(size_t)col * ldt + row] = (_Float16)v;
      }
    }
  }
}

// ---------------- fused per-node attention + head-mean + skip + residual + LN -------
// One wave per node; 32 lanes per edge, 2 edge slots in flight. Lane owns 8 contiguous
// channels (co = (lane&31)*8); (lane&31)<16 -> head 0 channels, else head 1.
// QK loop has ept folded out via per-node qe[ty] = scale*(q . e_ty) prologue.
__global__ __launch_bounds__(256) void node_attn_ln_kernel(
    const _Float16* __restrict__ QKVSh, const _Float16* __restrict__ epth,
    const float* __restrict__ hpre,
    const int* __restrict__ offs, const unsigned* __restrict__ epk,
    const float* __restrict__ gamma, const float* __restrict__ beta,
    _Float16* __restrict__ hlnh, int Nn) {
  __shared__ float sl0[4][CAP], sl1[4][CAP];
  __shared__ unsigned spk[4][CAP];
  __shared__ float sqeA[4][10], sqeB[4][10];
  __shared__ __align__(16) _Float16 elds[2560];
  const int tid = threadIdx.x;
  for (int t = tid; t < 1280; t += 256)
    reinterpret_cast<unsigned*>(elds)[t] = reinterpret_cast<const unsigned*>(epth)[t];
  __syncthreads();
  const int w = tid >> 6, lane = tid & 63;
  const int i = blockIdx.x * 4 + w;
  const int sub = lane >> 5;     // edge slot 0/1
  const int r = lane & 31;
  const int half = r >> 4;       // head of owned channels
  const int co = r << 3;         // channel offset, 8 ch per lane
  const float scale = 0.08838834764831845f;  // 1/sqrt(128)
  f16x8 qh = *reinterpret_cast<const f16x8*>(QKVSh + (size_t)i * QW + co);
  const f16x2* q2 = reinterpret_cast<const f16x2*>(&qh);
  // prologue: qe[ty] = scale * (q . e_ty), per head
#pragma unroll
  for (int ty = 0; ty < 10; ++ty) {
    f16x8 ev = *reinterpret_cast<const f16x8*>(elds + (ty << 8) + co);
    const f16x2* e2 = reinterpret_cast<const f16x2*>(&ev);
    float s = 0.f;
#pragma unroll
    for (int p2 = 0; p2 < 4; ++p2) s = fdot2f(q2[p2], e2[p2], s);
    s += __shfl_xor(s, 1); s += __shfl_xor(s, 2);
    s += __shfl_xor(s, 4); s += __shfl_xor(s, 8);
    if (lane == 0) sqeA[w][ty] = s * scale;
    if (lane == 16) sqeB[w][ty] = s * scale;
  }
  __threadfence_block();
  float m0 = -1e30f, m1 = -1e30f, s0 = 0.f, s1 = 0.f;
  float acc[8] = {0.f};
  const int ebeg = offs[i], eend = offs[i + 1];
  for (int cs = ebeg; cs < eend; cs += CAP) {
    const int cnt = min(CAP, eend - cs);
    for (int j = lane; j < cnt; j += 64) spk[w][j] = epk[cs + j];
    __threadfence_block();
    // --- QK phase: 2 edges per iteration, K-only dot + qe bias ---
    {
      int jj = (sub < cnt) ? sub : (cnt - 1);
      unsigned pk = spk[w][jj];
      int tyn = pk >> 18;
      f16x8 kv = *reinterpret_cast<const f16x8*>(QKVSh + (size_t)(pk & 0x3FFFF) * QW + 256 + co);
      for (int j = 0; j < cnt; j += 2) {
        f16x8 kc = kv;
        const int tyc = tyn;
        const bool valid = (j + sub) < cnt;
        int jn = j + 2 + sub; if (jn > cnt - 1) jn = cnt - 1;
        pk = spk[w][jn];
        tyn = pk >> 18;
        kv = *reinterpret_cast<const f16x8*>(QKVSh + (size_t)(pk & 0x3FFFF) * QW + 256 + co);
        const f16x2* k2 = reinterpret_cast<const f16x2*>(&kc);
        float d = 0.f;
#pragma unroll
        for (int p2 = 0; p2 < 4; ++p2) d = fdot2f(q2[p2], k2[p2], d);
        d += __shfl_xor(d, 1); d += __shfl_xor(d, 2);
        d += __shfl_xor(d, 4); d += __shfl_xor(d, 8);
        d = d * scale + (half ? sqeB[w][tyc] : sqeA[w][tyc]);
        if (valid) {
          if (r == 0) sl0[w][j + sub] = d;
          if (r == 16) sl1[w][j + sub] = d;
        }
      }
    }
    __threadfence_block();
    // chunk max
    float lm0 = -1e30f, lm1 = -1e30f;
    for (int j = lane; j < cnt; j += 64) {
      lm0 = fmaxf(lm0, sl0[w][j]); lm1 = fmaxf(lm1, sl1[w][j]);
    }
#pragma unroll
    for (int o = 32; o; o >>= 1) {
      lm0 = fmaxf(lm0, __shfl_xor(lm0, o)); lm1 = fmaxf(lm1, __shfl_xor(lm1, o));
    }
    const float nm0 = fmaxf(m0, lm0), nm1 = fmaxf(m1, lm1);
    const float r0 = __expf(m0 - nm0), r1 = __expf(m1 - nm1);
    const float rme = half ? r1 : r0;
    s0 *= r0; s1 *= r1;
#pragma unroll
    for (int t = 0; t < 8; ++t) acc[t] *= rme;
    m0 = nm0; m1 = nm1;
    // exp pass
    float ls0 = 0.f, ls1 = 0.f;
    for (int j = lane; j < cnt; j += 64) {
      float e0 = __expf(sl0[w][j] - m0);
      float e1 = __expf(sl1[w][j] - m1);
      sl0[w][j] = e0; sl1[w][j] = e1;
      ls0 += e0; ls1 += e1;
    }
#pragma unroll
    for (int o = 32; o; o >>= 1) { ls0 += __shfl_xor(ls0, o); ls1 += __shfl_xor(ls1, o); }
    s0 += ls0; s1 += ls1;
    __threadfence_block();
    // --- V phase: 2 edges per iteration, (v + e)*alpha ---
    {
      int jj = (sub < cnt) ? sub : (cnt - 1);
      unsigned pk = spk[w][jj];
      f16x8 vv = *reinterpret_cast<const f16x8*>(QKVSh + (size_t)(pk & 0x3FFFF) * QW + 512 + co);
      f16x8 ev = *reinterpret_cast<const f16x8*>(elds + ((pk >> 18) << 8) + co);
      for (int j = 0; j < cnt; j += 2) {
        f16x8 vc = vv, ec = ev;
        const int jcur = j + sub;
        float wj = 0.f;
        if (jcur < cnt) wj = half ? sl1[w][jcur] : sl0[w][jcur];
        int jn = j + 2 + sub; if (jn > cnt - 1) jn = cnt - 1;
        pk = spk[w][jn];
        vv = *reinterpret_cast<const f16x8*>(QKVSh + (size_t)(pk & 0x3FFFF) * QW + 512 + co);
        ev = *reinterpret_cast<const f16x8*>(elds + ((pk >> 18) << 8) + co);
#pragma unroll
        for (int t = 0; t < 8; ++t) acc[t] = fmaf((float)vc[t] + (float)ec[t], wj, acc[t]);
      }
    }
  }
  // combine slots, normalize, head-mean
  const float inv0 = 1.f / (s0 + 1e-16f), inv1 = 1.f / (s1 + 1e-16f);
  const float invme = half ? inv1 : inv0;
  float g[8];
#pragma unroll
  for (int t = 0; t < 8; ++t) {
    float a = acc[t] + __shfl_xor(acc[t], 32);
    a *= invme;
    g[t] = 0.5f * (a + __shfl_xor(a, 16));
  }
  const int cm = (r & 15) << 3;
  f16x8 sk = *reinterpret_cast<const f16x8*>(QKVSh + (size_t)i * QW + 768 + cm);
  float4 p0 = *reinterpret_cast<const float4*>(hpre + (size_t)i * DD + cm);
  float4 p1 = *reinterpret_cast<const float4*>(hpre + (size_t)i * DD + cm + 4);
  float xv[8];
  xv[0] = g[0] + (float)sk[0] + p0.x; xv[1] = g[1] + (float)sk[1] + p0.y;
  xv[2] = g[2] + (float)sk[2] + p0.z; xv[3] = g[3] + (float)sk[3] + p0.w;
  xv[4] = g[4] + (float)sk[4] + p1.x; xv[5] = g[5] + (float)sk[5] + p1.y;
  xv[6] = g[6] + (float)sk[6] + p1.z; xv[7] = g[7] + (float)sk[7] + p1.w;
  float sm = 0.f;
#pragma unroll
  for (int t = 0; t < 8; ++t) sm += xv[t];
  sm += __shfl_xor(sm, 1); sm += __shfl_xor(sm, 2);
  sm += __shfl_xor(sm, 4); sm += __shfl_xor(sm, 8);
  const float mu = sm * (1.f / 128.f);
  float dx[8], vvs = 0.f;
#pragma unroll
  for (int t = 0; t < 8; ++t) { dx[t] = xv[t] - mu; vvs += dx[t] * dx[t]; }
  vvs += __shfl_xor(vvs, 1); vvs += __shfl_xor(vvs, 2);
  vvs += __shfl_xor(vvs, 4); vvs += __shfl_xor(vvs, 8);
  const float rstd = rsqrtf(vvs * (1.f / 128.f) + 1e-6f);
  if (lane < 16) {
    float4 gm0 = *reinterpret_cast<const float4*>(gamma + cm);
    float4 gm1 = *reinterpret_cast<const float4*>(gamma + cm + 4);
    float4 bt0 = *reinterpret_cast<const float4*>(beta + cm);
    float4 bt1 = *reinterpret_cast<const float4*>(beta + cm + 4);
    f16x8 o;
    o[0] = (_Float16)(dx[0] * rstd * gm0.x + bt0.x);
    o[1] = (_Float16)(dx[1] * rstd * gm0.y + bt0.y);
    o[2] = (_Float16)(dx[2] * rstd * gm0.z + bt0.z);
    o[3] = (_Float16)(dx[3] * rstd * gm0.w + bt0.w);
    o[4] = (_Float16)(dx[4] * rstd * gm1.x + bt1.x);
    o[5] = (_Float16)(dx[5] * rstd * gm1.y + bt1.y);
    o[6] = (_Float16)(dx[6] * rstd * gm1.z + bt1.z);
    o[7] = (_Float16)(dx[7] * rstd * gm1.w + bt1.w);
    *reinterpret_cast<f16x8*>(hlnh + (size_t)i * DD + cm) = o;
  }
}

// ---------------- final: gather mask rows of hln1, apply layer-1 fused FFN ----------------
__global__ __launch_bounds__(128) void final_kernel(const _Float16* __restrict__ hlnh1,
                                                    const float* __restrict__ Wf,
                                                    const float* __restrict__ bfv,
                                                    const int* __restrict__ midx,
                                                    float* __restrict__ out) {
  __shared__ float rowv[128];
  const int b = blockIdx.x, j = threadIdx.x;
  const int row = midx[b];
  rowv[j] = (float)hlnh1[(size_t)row * DD + j];
  __syncthreads();
  const float* w1 = Wf + 16384 + j;  // Wf1[c][j]
  float s = bfv[128 + j];
#pragma unroll 4
  for (int c = 0; c < 128; ++c) s = fmaf(rowv[c], w1[c * 128], s);
  out[b * DD + j] = s;
}

extern "C" void kernel_launch(void* const* d_in, const int* in_sizes, int n_in,
                              void* d_out, int out_size, void* d_ws, size_t ws_size,
                              hipStream_t stream) {
  const float* x    = (const float*)d_in[0];
  const float* hemb = (const float*)d_in[1];
  const float* Wq   = (const float*)d_in[2];
  const float* bq   = (const float*)d_in[3];
  const float* Wk   = (const float*)d_in[4];
  const float* bk   = (const float*)d_in[5];
  const float* Wv   = (const float*)d_in[6];
  const float* bv   = (const float*)d_in[7];
  const float* We   = (const float*)d_in[8];
  const float* Wsk  = (const float*)d_in[9];
  const float* bsk  = (const float*)d_in[10];
  const float* lng  = (const float*)d_in[11];
  const float* lnb  = (const float*)d_in[12];
  const float* fw1  = (const float*)d_in[13];
  const float* fb1  = (const float*)d_in[14];
  const float* fw2  = (const float*)d_in[15];
  const float* fb2  = (const float*)d_in[16];
  const int* eidx   = (const int*)d_in[17];
  const int* etyp   = (const int*)d_in[18];
  const int* midx   = (const int*)d_in[19];

  const int Nn = in_sizes[0] / DD;     // 16000
  const int E = in_sizes[18];          // 256000

  const int* esrc = eidx;
  const int* edst = eidx + E;

  char* p = (char*)d_ws;
  auto alloc = [&](size_t bytes) -> void* {
    void* r = (void*)p;
    p += (bytes + 255) & ~(size_t)255;
    return r;
  };
  _Float16* QKVSh = (_Float16*)alloc((size_t)Nn * QW * 2);
  _Float16* xh    = (_Float16*)alloc((size_t)Nn * DD * 2);
  _Float16* hln0  = (_Float16*)alloc((size_t)Nn * DD * 2);
  _Float16* hln1  = (_Float16*)alloc((size_t)Nn * DD * 2);
  float*    h1    = (float*)alloc((size_t)Nn * DD * 4);
  _Float16* WcatT = (_Float16*)alloc((size_t)QW * DD * 2);
  float*    Wcat  = (float*)alloc((size_t)DD * QW * 4);
  float*    bcat  = (float*)alloc(QW * 4);
  _Float16* epth  = (_Float16*)alloc(2560 * 2);
  _Float16* fw1h  = (_Float16*)alloc((size_t)2 * DD * 512 * 2);
  _Float16* fw2Th = (_Float16*)alloc((size_t)2 * DD * 512 * 2);
  float*    Wf    = (float*)alloc(2 * 128 * 128 * 4);
  _Float16* Wfh   = (_Float16*)alloc(128 * 128 * 2);
  float*    bfv   = (float*)alloc(256 * 4);
  float*    bzero = (float*)alloc(1024 * 4);
  _Float16* BtMid = (_Float16*)alloc((size_t)1024 * 128 * 2);
  float*    bmid  = (float*)alloc(1024 * 4);
  int* counts = (int*)alloc((size_t)Nn * 4);
  int* offs   = (int*)alloc((size_t)(Nn + 1) * 4);
  int* cursor = (int*)alloc((size_t)Nn * 4);
  unsigned* epk = (unsigned*)alloc((size_t)E * 4);

  // CSR
  hipMemsetAsync(counts, 0, (size_t)Nn * sizeof(int), stream);
  count_kernel<<<(E + 255) / 256, 256, 0, stream>>>(edst, counts, E);
  scan_kernel<<<1, 1024, 0, stream>>>(counts, offs, cursor, Nn);
  scatter_kernel<<<(E + 255) / 256, 256, 0, stream>>>(edst, esrc, etyp, cursor, epk, E);

  // Precompute
  const int pc_threads = 256 + 2560 + 114688 + 896 + 1024 + 16384 + 131072 + Nn * 16;
  pp_cast<<<(pc_threads + 255) / 256, 256, 0, stream>>>(
      Wq, Wk, Wv, Wsk, bq, bk, bv, bsk, hemb, We, x, fw1, fb1, fw2, fb2,
      WcatT, Wcat, bcat, epth, xh, fw1h, fw2Th, bfv, bzero, Nn);
  pp_bmid<<<4, 256, 0, stream>>>(bfv, Wcat, bcat, bmid);
  // Wf[l] = fw1[l] @ fw2[l] (MFMA); l=0 also emits Wfh + BtMid[0:128] (transposed)
  gemm_tn_f16<<<dim3(1, 1), 256, 0, stream>>>(fw1h, fw2Th, bzero,
                                              Wf, 128, Wfh, 0, 128, BtMid, 128,
                                              128, 128, 512);
  gemm_tn_f16<<<dim3(1, 1), 256, 0, stream>>>(fw1h + 65536, fw2Th + 65536, bzero,
                                              Wf + 16384, 128, nullptr, 0, 0, nullptr, 0,
                                              128, 128, 512);
  // BtMid[128:1024] = (Wf0 @ Wcat)^T
  gemm_tn_f16<<<dim3(1, 7), 256, 0, stream>>>(Wfh, WcatT, bzero,
                                              nullptr, 0, nullptr, 0, 0, BtMid + 16384, 128,
                                              128, 896, 128);

  // Layer 0
  dim3 g1(Nn / 128, QW / 128);
  gemm_tn_f16<<<g1, 256, 0, stream>>>(xh, WcatT, bcat, nullptr, 0, QKVSh, 0, QW,
                                      nullptr, 0, Nn, QW, DD);
  node_attn_ln_kernel<<<Nn / 4, 256, 0, stream>>>(QKVSh, epth, x, offs, epk,
                                                  lng, lnb, hln0, Nn);
  // Fused: [h1 (f32) | QKVS1 (f16)] = hln0 @ [Wf0 | Wf0@Wcat] + bmid
  dim3 g2(Nn / 128, 1024 / 128);
  gemm_tn_f16<<<g2, 256, 0, stream>>>(hln0, BtMid, bmid, h1, 128, QKVSh, 128, QW,
                                      nullptr, 0, Nn, 1024, DD);
  node_attn_ln_kernel<<<Nn / 4, 256, 0, stream>>>(QKVSh, epth, h1, offs, epk,
                                                  lng + DD, lnb + DD, hln1, Nn);
  final_kernel<<<64, 128, 0, stream>>>(hln1, Wf, bfv, midx, (float*)d_out);
}